// Round 1
// baseline (3203.863 us; speedup 1.0000x reference)
//
#include <hip/hip_runtime.h>
#include <cmath>

#define Wd 256
#define Hd 256
#define HWd 65536
#define NSL 64                 // B*C
#define NTOT 4194304           // NSL*HWd
#define NBLK 4096              // 8*8*64 tiles
#define TILE 32

#define C_COUP (2.0f / 4194304.0f)       // 2*COUPLING/N
#define C_KIN  (0.2f / 4194304.0f)       // 2*ALPHA/N
#define C_VOID 0.0098f                   // 2*GAMMA^2

__device__ __forceinline__ void block_reduce_write(float sumx, float sumy,
                                                   float* partX, float* partY,
                                                   int bid, float* sRed) {
    // wave-64 reduce
    for (int off = 32; off > 0; off >>= 1) {
        sumx += __shfl_down(sumx, off, 64);
        sumy += __shfl_down(sumy, off, 64);
    }
    int tid = threadIdx.x;
    int wid = tid >> 6;
    if ((tid & 63) == 0) { sRed[wid] = sumx; sRed[4 + wid] = sumy; }
    __syncthreads();
    if (tid == 0) {
        partX[bid] = sRed[0] + sRed[1] + sRed[2] + sRed[3];
        partY[bid] = sRed[4] + sRed[5] + sRed[6] + sRed[7];
    }
}

__global__ __launch_bounds__(256)
void k_init(const float* __restrict__ px0, const float* __restrict__ py0,
            float* __restrict__ pxA, float* __restrict__ pyA,
            float* __restrict__ mx, float* __restrict__ my,
            float* __restrict__ vx, float* __restrict__ vy,
            float* __restrict__ partX, float* __restrict__ partY) {
    __shared__ float sRed[8];
    int tid = threadIdx.x;
    int base = blockIdx.x * 1024;
    float sx = 0.f, sy = 0.f;
#pragma unroll
    for (int i = 0; i < 4; ++i) {
        int idx = base + i * 256 + tid;
        float x = px0[idx], y = py0[idx];
        pxA[idx] = x; pyA[idx] = y;
        mx[idx] = 0.f; my[idx] = 0.f; vx[idx] = 0.f; vy[idx] = 0.f;
        sx += x * x; sy += y * y;
    }
    block_reduce_write(sx, sy, partX, partY, blockIdx.x, sRed);
}

__global__ __launch_bounds__(256)
void k_scalar(const float* __restrict__ partX, const float* __restrict__ partY,
              float* __restrict__ coef) {
    __shared__ double rx[256], ry[256];
    int tid = threadIdx.x;
    double ax = 0.0, ay = 0.0;
    for (int i = tid; i < NBLK; i += 256) { ax += (double)partX[i]; ay += (double)partY[i]; }
    rx[tid] = ax; ry[tid] = ay;
    __syncthreads();
    for (int s = 128; s > 0; s >>= 1) {
        if (tid < s) { rx[tid] += rx[tid + s]; ry[tid] += ry[tid + s]; }
        __syncthreads();
    }
    if (tid == 0) {
        double nx = sqrt(rx[0]), ny = sqrt(ry[0]);
        double pn = nx + ny;
        double u = pn * pn - 0.01;                       // V^2 = 0.01
        double sgn = (u > 0.0) ? 1.0 : ((u < 0.0) ? -1.0 : 0.0);
        coef[0] = (float)(0.2 * sgn * pn / nx);          // 2*BETA*sgn*(nx+ny)/nx
        coef[1] = (float)(0.2 * sgn * pn / ny);
    }
}

__global__ __launch_bounds__(256)
void k_step(const float* __restrict__ S,
            const float* __restrict__ pxin, const float* __restrict__ pyin,
            float* __restrict__ pxout, float* __restrict__ pyout,
            float* __restrict__ mx, float* __restrict__ my,
            float* __restrict__ vx, float* __restrict__ vy,
            float* __restrict__ partX, float* __restrict__ partY,
            const float* __restrict__ coef,
            float a_step, float inv_bc2,
            int write_sp, float* __restrict__ sp) {
    __shared__ float sP[36][37];
    __shared__ float sC1[34][35];
    __shared__ float sC2[34][35];
    __shared__ float sRed[8];

    const int tid = threadIdx.x;
    const int x0 = blockIdx.x * TILE;
    const int y0 = blockIdx.y * TILE;
    const int z = blockIdx.z;
    const size_t base = (size_t)z * HWd;

    const float coefx = coef[0], coefy = coef[1];
    const int c = tid & 31;
    const int r0 = tid >> 5;

    float dKx[4], dKy[4], pxv[4], pyv[4];

    // ================= field X =================
    for (int i = tid; i < 36 * 36; i += 256) {
        int u = i / 36, v = i - u * 36;
        int gy = y0 - 2 + u, gx = x0 - 2 + v;
        float val = 0.f;
        if ((unsigned)gy < (unsigned)Hd && (unsigned)gx < (unsigned)Wd)
            val = pxin[base + (size_t)gy * Wd + gx];
        sP[u][v] = val;
    }
    __syncthreads();
    for (int i = tid; i < 34 * 34; i += 256) {
        int a = i / 34, b = i - a * 34;
        int gy = y0 - 1 + a, gx = x0 - 1 + b;
        float c1 = 0.f, c2 = 0.f;
        if ((unsigned)gy < (unsigned)Hd && (unsigned)gx < (unsigned)Wd) {
            float tl = sP[a][b],     tc = sP[a][b + 1],     tr = sP[a][b + 2];
            float ml = sP[a + 1][b],                        mr = sP[a + 1][b + 2];
            float bl = sP[a + 2][b], bc_ = sP[a + 2][b + 1], br = sP[a + 2][b + 2];
            c1 = 0.125f * (tr - tl) + 0.25f * (mr - ml) + 0.125f * (br - bl);
            c2 = 0.125f * (bl - tl) + 0.25f * (bc_ - tc) + 0.125f * (br - tr);
        }
        sC1[a][b] = c1; sC2[a][b] = c2;
    }
    __syncthreads();
#pragma unroll
    for (int ii = 0; ii < 4; ++ii) {
        int r = r0 + 8 * ii;
        pxv[ii] = sP[r + 2][c + 2];
        float d1 = 0.125f * (sC1[r][c + 2] - sC1[r][c]) +
                   0.25f  * (sC1[r + 1][c + 2] - sC1[r + 1][c]) +
                   0.125f * (sC1[r + 2][c + 2] - sC1[r + 2][c]);
        float d2 = 0.125f * (sC2[r + 2][c] - sC2[r][c]) +
                   0.25f  * (sC2[r + 2][c + 1] - sC2[r][c + 1]) +
                   0.125f * (sC2[r + 2][c + 2] - sC2[r][c + 2]);
        dKx[ii] = d1 + d2;
    }
    __syncthreads();

    // ================= field Y =================
    for (int i = tid; i < 36 * 36; i += 256) {
        int u = i / 36, v = i - u * 36;
        int gy = y0 - 2 + u, gx = x0 - 2 + v;
        float val = 0.f;
        if ((unsigned)gy < (unsigned)Hd && (unsigned)gx < (unsigned)Wd)
            val = pyin[base + (size_t)gy * Wd + gx];
        sP[u][v] = val;
    }
    __syncthreads();
    for (int i = tid; i < 34 * 34; i += 256) {
        int a = i / 34, b = i - a * 34;
        int gy = y0 - 1 + a, gx = x0 - 1 + b;
        float c1 = 0.f, c2 = 0.f;
        if ((unsigned)gy < (unsigned)Hd && (unsigned)gx < (unsigned)Wd) {
            float tl = sP[a][b],     tc = sP[a][b + 1],     tr = sP[a][b + 2];
            float ml = sP[a + 1][b],                        mr = sP[a + 1][b + 2];
            float bl = sP[a + 2][b], bc_ = sP[a + 2][b + 1], br = sP[a + 2][b + 2];
            c1 = 0.125f * (tr - tl) + 0.25f * (mr - ml) + 0.125f * (br - bl);
            c2 = 0.125f * (bl - tl) + 0.25f * (bc_ - tc) + 0.125f * (br - tr);
        }
        sC1[a][b] = c1; sC2[a][b] = c2;
    }
    __syncthreads();
#pragma unroll
    for (int ii = 0; ii < 4; ++ii) {
        int r = r0 + 8 * ii;
        pyv[ii] = sP[r + 2][c + 2];
        float d1 = 0.125f * (sC1[r][c + 2] - sC1[r][c]) +
                   0.25f  * (sC1[r + 1][c + 2] - sC1[r + 1][c]) +
                   0.125f * (sC1[r + 2][c + 2] - sC1[r + 2][c]);
        float d2 = 0.125f * (sC2[r + 2][c] - sC2[r][c]) +
                   0.25f  * (sC2[r + 2][c + 1] - sC2[r][c + 1]) +
                   0.125f * (sC2[r + 2][c + 2] - sC2[r][c + 2]);
        dKy[ii] = d1 + d2;
    }

    // ================ pointwise grad + Adam ================
    float sumx = 0.f, sumy = 0.f;
#pragma unroll
    for (int ii = 0; ii < 4; ++ii) {
        int r = r0 + 8 * ii;
        int gy = y0 + r, gx = x0 + c;
        size_t idx = base + (size_t)gy * Wd + gx;
        float s = S[idx];
        float dxv = (gx + 1 < Wd) ? (S[idx + 1] - s) : 0.f;
        float dyv = (gy + 1 < Hd) ? (S[idx + Wd] - s) : 0.f;
        float R = pxv[ii] * dxv + pyv[ii] * dyv;
        float vm = (s < 0.05f) ? 1.f : 0.f;

        float gxg = C_COUP * R * dxv - C_KIN * dKx[ii] + coefx * pxv[ii] + C_VOID * vm * pxv[ii];
        float gyg = C_COUP * R * dyv - C_KIN * dKy[ii] + coefy * pyv[ii] + C_VOID * vm * pyv[ii];

        float m1 = 0.9f * mx[idx] + 0.1f * gxg;
        float v1 = 0.999f * vx[idx] + 0.001f * gxg * gxg;
        mx[idx] = m1; vx[idx] = v1;
        float pnx = pxv[ii] - a_step * m1 / (sqrtf(v1 * inv_bc2) + 1e-8f);
        pxout[idx] = pnx; sumx += pnx * pnx;

        float m2 = 0.9f * my[idx] + 0.1f * gyg;
        float v2 = 0.999f * vy[idx] + 0.001f * gyg * gyg;
        my[idx] = m2; vy[idx] = v2;
        float pny = pyv[ii] - a_step * m2 / (sqrtf(v2 * inv_bc2) + 1e-8f);
        pyout[idx] = pny; sumy += pny * pny;

        if (write_sp) sp[idx] = s + R;
    }
    __syncthreads();  // protect sRed reuse ordering
    int bid = (z * 8 + blockIdx.y) * 8 + blockIdx.x;
    block_reduce_write(sumx, sumy, partX, partY, bid, sRed);
}

extern "C" void kernel_launch(void* const* d_in, const int* in_sizes, int n_in,
                              void* d_out, int out_size, void* d_ws, size_t ws_size,
                              hipStream_t stream) {
    (void)in_sizes; (void)n_in; (void)out_size; (void)ws_size;
    const float* S   = (const float*)d_in[0];
    const float* px0 = (const float*)d_in[1];
    const float* py0 = (const float*)d_in[2];
    float* out = (float*)d_out;

    float* sp     = out;                          // slot 0: Sp
    float* outA_x = out + (size_t)NTOT;           // slot 1: phi_x post
    float* outA_y = out + 2 * (size_t)NTOT;       // slot 2: phi_y post
    float* outB_x = out + 3 * (size_t)NTOT;       // slot 3: phi_x pre
    float* outB_y = out + 4 * (size_t)NTOT;       // slot 4: phi_y pre

    float* ws = (float*)d_ws;
    float* mx = ws;
    float* my = mx + (size_t)NTOT;
    float* vx = my + (size_t)NTOT;
    float* vy = vx + (size_t)NTOT;
    float* partX = vy + (size_t)NTOT;
    float* partY = partX + NBLK;
    float* coef  = partY + NBLK;

    dim3 grid(8, 8, 64), blk(256, 1, 1);

    k_init<<<NBLK, 256, 0, stream>>>(px0, py0, outA_x, outA_y, mx, my, vx, vy, partX, partY);
    k_scalar<<<1, 256, 0, stream>>>(partX, partY, coef);

    for (int t = 1; t <= 50; ++t) {
        double bc1 = 1.0 - pow(0.9, (double)t);
        double bc2 = 1.0 - pow(0.999, (double)t);
        float a_step = (float)(0.05 / bc1);
        float inv_bc2 = (float)(1.0 / bc2);
        bool odd = (t & 1) != 0;
        const float* pix = odd ? outA_x : outB_x;
        const float* piy = odd ? outA_y : outB_y;
        float* pox = odd ? outB_x : outA_x;
        float* poy = odd ? outB_y : outA_y;
        k_step<<<grid, blk, 0, stream>>>(S, pix, piy, pox, poy,
                                         mx, my, vx, vy, partX, partY, coef,
                                         a_step, inv_bc2, (t == 50) ? 1 : 0, sp);
        if (t < 50)
            k_scalar<<<1, 256, 0, stream>>>(partX, partY, coef);
    }
}